// Round 9
// baseline (129.394 us; speedup 1.0000x reference)
//
#include <hip/hip_runtime.h>

#define NN 2048
#define CC 64
#define TT 64
#define NROWS  (16 * 2048)

// ---------- Kernel A: E[row][t] = q[row,:] . pos_emb[:,t], 4 rows/wave ----------
__global__ __launch_bounds__(256, 4) void e_kernel(
    const float* __restrict__ q,
    const float* __restrict__ pos_emb,
    float* __restrict__ E)
{
    const int lane = threadIdx.x & 63;
    const int wv   = threadIdx.x >> 6;
    const int wid  = blockIdx.x * 4 + wv;      // [0, 8192)
#pragma unroll
    for (int r = 0; r < 4; ++r) {
        const int row  = wid + r * 8192;
        const int urow = __builtin_amdgcn_readfirstlane(row);
        const float* qr = q + (size_t)urow * CC;
        const float* pe = pos_emb + lane;
        float acc0 = 0.f, acc1 = 0.f, acc2 = 0.f, acc3 = 0.f;
#pragma unroll
        for (int c = 0; c < CC; c += 4) {
            acc0 = fmaf(qr[c + 0], pe[(c + 0) * TT], acc0);
            acc1 = fmaf(qr[c + 1], pe[(c + 1) * TT], acc1);
            acc2 = fmaf(qr[c + 2], pe[(c + 2) * TT], acc2);
            acc3 = fmaf(qr[c + 3], pe[(c + 3) * TT], acc3);
        }
        E[(size_t)urow * TT + lane] = (acc0 + acc1) + (acc2 + acc3);
    }
}

// ---------- interp helper: 8 outputs from one chunk ----------
__device__ __forceinline__ void interp8(const float* __restrict__ elds,
                                        const float* __restrict__ g8,
                                        float base, float4& o0, float4& o1)
{
    if (base >= 63.0f) {                 // all 8 clamp to E[63]
        const float e63 = elds[63];
        o0 = make_float4(e63, e63, e63, e63);
        o1 = o0;
    } else {
        float r[8];
        float run = 0.f;
#pragma unroll
        for (int k = 7; k >= 0; --k) {
            run += g8[k];
            float P  = fminf(run + base, 63.0f);
            float fl = floorf(P);
            float w  = P - fl;
            int   i0 = (int)fl;
            int   i1 = min(i0 + 1, 63);
            float ef = elds[i0], ec = elds[i1];
            r[k] = fmaf(w, ec - ef, ef);
        }
        o0 = make_float4(r[0], r[1], r[2], r[3]);
        o1 = make_float4(r[4], r[5], r[6], r[7]);
    }
}

// ---------- Kernel B: one wave = one full row, ZERO barriers ----------
__global__ __launch_bounds__(256, 4) void cope_wave(
    const float* __restrict__ qk,
    const float* __restrict__ E,
    float* __restrict__ out)
{
    const int tid  = threadIdx.x;
    const int lane = tid & 63;
    const int wv   = tid >> 6;
    const int row  = blockIdx.x * 4 + wv;     // one row per wave

    __shared__ float elds_s[4][TT];           // wave-private stripes, no sync
    float* elds = elds_s[wv];

    // ---- full row: 4 chunks of 512 elements; lane owns 8 contiguous per chunk ----
    // chunk k: float4 indices k*128 + 2*lane, k*128 + 2*lane + 1
    const float4* p = (const float4*)(qk + (size_t)row * NN);
    float4 c0 = p[        2*lane], c1 = p[        2*lane + 1];
    float4 c2 = p[128   + 2*lane], c3 = p[128   + 2*lane + 1];
    float4 c4 = p[256   + 2*lane], c5 = p[256   + 2*lane + 1];
    float4 c6 = p[384   + 2*lane], c7 = p[384   + 2*lane + 1];
    const float ecur = E[(size_t)row * TT + lane];

    elds[lane] = ecur;

    // ---- sigmoid of 32 elements + per-chunk sums ----
    float g[32];
    g[ 0]=c0.x; g[ 1]=c0.y; g[ 2]=c0.z; g[ 3]=c0.w;
    g[ 4]=c1.x; g[ 5]=c1.y; g[ 6]=c1.z; g[ 7]=c1.w;
    g[ 8]=c2.x; g[ 9]=c2.y; g[10]=c2.z; g[11]=c2.w;
    g[12]=c3.x; g[13]=c3.y; g[14]=c3.z; g[15]=c3.w;
    g[16]=c4.x; g[17]=c4.y; g[18]=c4.z; g[19]=c4.w;
    g[20]=c5.x; g[21]=c5.y; g[22]=c5.z; g[23]=c5.w;
    g[24]=c6.x; g[25]=c6.y; g[26]=c6.z; g[27]=c6.w;
    g[28]=c7.x; g[29]=c7.y; g[30]=c7.z; g[31]=c7.w;

    float t0 = 0.f, t1 = 0.f, t2 = 0.f, t3 = 0.f;
#pragma unroll
    for (int j = 0; j < 8; ++j) {
        g[j]      = __builtin_amdgcn_rcpf(1.f + __expf(-g[j]));      t0 += g[j];
        g[8 + j]  = __builtin_amdgcn_rcpf(1.f + __expf(-g[8 + j]));  t1 += g[8 + j];
        g[16 + j] = __builtin_amdgcn_rcpf(1.f + __expf(-g[16 + j])); t2 += g[16 + j];
        g[24 + j] = __builtin_amdgcn_rcpf(1.f + __expf(-g[24 + j])); t3 += g[24 + j];
    }

    // ---- quad wave-level inclusive suffix scan (one butterfly, 4 chains) ----
    float i0 = t0, i1 = t1, i2 = t2, i3 = t3;
#pragma unroll
    for (int o = 1; o < 64; o <<= 1) {
        float a = __shfl_down(i0, o, 64);
        float b = __shfl_down(i1, o, 64);
        float c = __shfl_down(i2, o, 64);
        float d = __shfl_down(i3, o, 64);
        if (lane + o < 64) { i0 += a; i1 += b; i2 += c; i3 += d; }
    }
    const float T1 = __shfl(i1, 0, 64);     // chunk totals
    const float T2 = __shfl(i2, 0, 64);
    const float T3 = __shfl(i3, 0, 64);
    const float base3 = i3 - t3;            // exclusive suffix per chunk segment
    const float base2 = i2 - t2 + T3;
    const float base1 = i1 - t1 + T2 + T3;
    const float base0 = i0 - t0 + T1 + T2 + T3;

    // ---- per-chunk clamp fast-path + interp, store ----
    float4* op = (float4*)(out + (size_t)row * NN);
    float4 o0, o1;
    interp8(elds, g,      base0, o0, o1);
    op[        2*lane] = o0;  op[        2*lane + 1] = o1;
    interp8(elds, g + 8,  base1, o0, o1);
    op[128   + 2*lane] = o0;  op[128   + 2*lane + 1] = o1;
    interp8(elds, g + 16, base2, o0, o1);
    op[256   + 2*lane] = o0;  op[256   + 2*lane + 1] = o1;
    interp8(elds, g + 24, base3, o0, o1);
    op[384   + 2*lane] = o0;  op[384   + 2*lane + 1] = o1;
}

// ---------- Fallback (ws too small): round-1 fused kernel ----------
__global__ __launch_bounds__(256, 4) void cope_fused(
    const float* __restrict__ q,
    const float* __restrict__ qk,
    const float* __restrict__ pos_emb,
    float* __restrict__ out)
{
    const int tid  = threadIdx.x;
    const int lane = tid & 63;
    const int wv   = tid >> 6;
    const int row  = blockIdx.x;

    __shared__ float q_lds[CC];
    __shared__ float e_part[4][TT];
    __shared__ float e_row[TT];
    __shared__ float wave_tot[4];

    const size_t rowN = (size_t)row * NN;
    const float4* qk4 = (const float4*)(qk + rowN);
    float4 v0 = qk4[tid * 2];
    float4 v1 = qk4[tid * 2 + 1];

    if (tid < CC) q_lds[tid] = q[(size_t)row * CC + tid];
    __syncthreads();
    {
        const int t  = tid & 63;
        const int c0 = (tid >> 6) * 16;
        float acc = 0.0f;
#pragma unroll
        for (int cc = 0; cc < 16; ++cc)
            acc = fmaf(q_lds[c0 + cc], pos_emb[(c0 + cc) * TT + t], acc);
        e_part[tid >> 6][t] = acc;
    }
    __syncthreads();
    if (tid < TT)
        e_row[tid] = e_part[0][tid] + e_part[1][tid] + e_part[2][tid] + e_part[3][tid];

    float g[8];
    g[0] = v0.x; g[1] = v0.y; g[2] = v0.z; g[3] = v0.w;
    g[4] = v1.x; g[5] = v1.y; g[6] = v1.z; g[7] = v1.w;
#pragma unroll
    for (int k = 0; k < 8; ++k)
        g[k] = 1.0f / (1.0f + __expf(-g[k]));

    float s = 0.0f;
#pragma unroll
    for (int k = 0; k < 8; ++k) s += g[k];

    float inc = s;
#pragma unroll
    for (int o = 1; o < 64; o <<= 1) {
        float tmp = __shfl_down(inc, o, 64);
        if (lane + o < 64) inc += tmp;
    }
    const float X = inc - s;
    if (lane == 0) wave_tot[wv] = inc;
    __syncthreads();

    float W = 0.0f;
#pragma unroll
    for (int w2 = 0; w2 < 4; ++w2)
        if (w2 > wv) W += wave_tot[w2];
    const float base = X + W;

    float o8[8];
    float run = 0.0f;
#pragma unroll
    for (int k = 7; k >= 0; --k) {
        run += g[k];
        float P  = fminf(run + base, 63.0f);
        float fl = floorf(P);
        float w_ = P - fl;
        int   i0 = (int)fl;
        int   i1 = (int)ceilf(P);
        float ef = e_row[i0];
        float ec = e_row[i1];
        o8[k] = fmaf(w_, ec - ef, ef);
    }

    float4* out4 = (float4*)(out + rowN);
    out4[tid * 2]     = make_float4(o8[0], o8[1], o8[2], o8[3]);
    out4[tid * 2 + 1] = make_float4(o8[4], o8[5], o8[6], o8[7]);
}

extern "C" void kernel_launch(void* const* d_in, const int* in_sizes, int n_in,
                              void* d_out, int out_size, void* d_ws, size_t ws_size,
                              hipStream_t stream) {
    const float* q       = (const float*)d_in[0];
    const float* qk      = (const float*)d_in[1];
    const float* pos_emb = (const float*)d_in[2];
    float* out = (float*)d_out;

    const size_t e_bytes = (size_t)NROWS * TT * sizeof(float);
    if (ws_size >= e_bytes) {
        float* E = (float*)d_ws;
        e_kernel<<<dim3(2048), dim3(256), 0, stream>>>(q, pos_emb, E);
        cope_wave<<<dim3(NROWS / 4), dim3(256), 0, stream>>>(qk, E, out);
    } else {
        cope_fused<<<dim3(NROWS), dim3(256), 0, stream>>>(q, qk, pos_emb, out);
    }
}